// Round 8
// baseline (897.304 us; speedup 1.0000x reference)
//
#include <hip/hip_runtime.h>

#define BB 4
#define CY 256
#define CM 128
#define HW 4096       // 64*64
#define HWy 1024      // 32*32
#define PHW 4356      // 66*66
#define EPSF 1e-5f
#define TWOPI 6.2831853071795864769f

struct c32 { float re, im; };

// ---------------- conv kernels ----------------

__global__ void conv1_kernel(const float* __restrict__ y, const float* __restrict__ w,
                             const float* __restrict__ g, const float* __restrict__ bb,
                             const float* __restrict__ m, const float* __restrict__ v,
                             float* __restrict__ y1){
  int p = blockIdx.x*256 + threadIdx.x;   // 0..1023
  int ocb = blockIdx.y*8;
  int b = blockIdx.z;
  float acc[8] = {0,0,0,0,0,0,0,0};
  const float* yb = y + (size_t)b*CY*HWy + p;
  #pragma unroll 4
  for(int ic=0; ic<CY; ic++){
    float xv = yb[(size_t)ic*HWy];
    #pragma unroll
    for(int j=0;j<8;j++) acc[j] += xv * w[(ocb+j)*CY + ic];
  }
  #pragma unroll
  for(int j=0;j<8;j++){
    int oc = ocb+j;
    float s = g[oc]*rsqrtf(v[oc]+EPSF);
    float bi = bb[oc] - m[oc]*s;
    float r = acc[j]*s + bi;
    y1[((size_t)(b*CM+oc))*HWy + p] = r>0.f?r:0.f;
  }
}

// v6: oc-coverage 8 -> 32 per block (grid.y 16 -> 4): y1 re-read 16x -> 4x.
__global__ void qconv_kernel(const float* __restrict__ y1, const float* __restrict__ w,
                             float* __restrict__ q){
  int p = blockIdx.x*256 + threadIdx.x;  // 0..4095
  int ocb = blockIdx.y*32; int b = blockIdx.z;
  int mi = ((p>>7)<<5) + ((p&63)>>1);    // (h/2)*32 + w/2
  float acc[32];
  #pragma unroll
  for(int j=0;j<32;j++) acc[j]=0.f;
  const float* yb = y1 + (size_t)b*CM*HWy + mi;
  for(int ic=0; ic<CM; ic++){
    float xv = yb[(size_t)ic*HWy];
    #pragma unroll
    for(int j=0;j<32;j++) acc[j] += xv * w[(ocb+j)*CM+ic];
  }
  #pragma unroll
  for(int j=0;j<32;j++) q[((size_t)(b*CM+ocb+j))*HW + p] = acc[j];
}

// v6: oc-coverage 8 -> 32 per block (grid.y 16 -> 4): x re-read 16x -> 4x
// (x = 8MB > 4MB per-XCD L2, so the redundancy was L3-priced).
__global__ void kvconv_kernel(const float* __restrict__ x, const float* __restrict__ kw,
                              const float* __restrict__ vw,
                              float* __restrict__ k, float* __restrict__ v){
  int p = blockIdx.x*256 + threadIdx.x;  // 0..4355 (guard)
  int ocb = blockIdx.y*32; int b = blockIdx.z;
  if(p >= PHW) return;
  int hh = p/66, ww2 = p - hh*66;
  int ih = hh-1, iw = ww2-1;
  bool inb = (ih>=0 && ih<64 && iw>=0 && iw<64);
  float acck[32], accv[32];
  #pragma unroll
  for(int j=0;j<32;j++){ acck[j]=0.f; accv[j]=0.f; }
  if(inb){
    const float* xb = x + (size_t)b*CM*HW + ih*64 + iw;
    for(int ic=0; ic<CM; ic++){
      float xv = xb[(size_t)ic*HW];
      #pragma unroll
      for(int j=0;j<32;j++){ acck[j] += xv*kw[(ocb+j)*CM+ic]; accv[j] += xv*vw[(ocb+j)*CM+ic]; }
    }
  }
  #pragma unroll
  for(int j=0;j<32;j++){
    size_t o = ((size_t)(b*CM+ocb+j))*PHW + p;
    k[o]=acck[j]; v[o]=accv[j];
  }
}

// ---------------- attention ----------------

__global__ void attn_kernel(const float* __restrict__ q, const float* __restrict__ k,
                            const float* __restrict__ v, const float* __restrict__ relh,
                            const float* __restrict__ relw, float* __restrict__ xatt){
  int t = blockIdx.x*256 + threadIdx.x;  // over B*CM*HW
  int p = t & 4095;
  int bc = t >> 12;       // b*128+c
  int c = bc & 127;
  int h = p>>6, w2 = p&63;
  float qv = q[(size_t)bc*HW + p];
  const float* kb = k + (size_t)bc*PHW;
  const float* vb = v + (size_t)bc*PHW;
  float lg[9], vv[9];
  #pragma unroll
  for(int ti=0; ti<3; ti++){
    #pragma unroll
    for(int tj=0; tj<3; tj++){
      int idx = (h+ti)*66 + (w2+tj);
      float rel = (c<64) ? relh[c*3+ti] : relw[(c-64)*3+tj];
      float kv = kb[idx] + rel;
      lg[ti*3+tj] = qv*kv;
      vv[ti*3+tj] = vb[idx];
    }
  }
  float mx = lg[0];
  #pragma unroll
  for(int i=1;i<9;i++) mx = fmaxf(mx, lg[i]);
  float s=0.f, o=0.f;
  #pragma unroll
  for(int i=0;i<9;i++){ float e = __expf(lg[i]-mx); s += e; o += e*vv[i]; }
  xatt[t] = o/s;
}

// ---------------- FFT helpers ----------------

template<int SIGN>
__device__ inline void dft8(const c32* a, c32* X){
  constexpr float C8[8] = {1.f,0.70710678118654752f,0.f,-0.70710678118654752f,
                           -1.f,-0.70710678118654752f,0.f,0.70710678118654752f};
  constexpr float S8[8] = {0.f,0.70710678118654752f,1.f,0.70710678118654752f,
                           0.f,-0.70710678118654752f,-1.f,-0.70710678118654752f};
  #pragma unroll
  for(int kk=0;kk<8;kk++){
    float xr=0.f, xi=0.f;
    #pragma unroll
    for(int n=0;n<8;n++){
      const int j=(n*kk)&7;
      const float wr = C8[j];
      const float wi = SIGN*S8[j];   // e^{SIGN*2pi i j/8}
      xr += a[n].re*wr - a[n].im*wi;
      xi += a[n].re*wi + a[n].im*wr;
    }
    X[kk].re=xr; X[kk].im=xi;
  }
}

// 64-pt FFT along an axis; 32 lines/block x 8 threads; line l: base=(l/l_div)*s1+(l%l_div)*s2
template<int SIGN, bool RIN, bool ROUT>
__global__ void fft64_kernel(const float* in, float* out,
                             int l_div, int s1, int s2, int estride, float scale){
  __shared__ c32 tmp[32][65];
  int ll = threadIdx.x & 31;
  int j  = threadIdx.x >> 5;   // n2 in pass1, k1 in pass2
  int l = blockIdx.x*32 + ll;
  int base = (l/l_div)*s1 + (l%l_div)*s2;
  c32 a[8];
  #pragma unroll
  for(int n1=0;n1<8;n1++){
    int e = n1*8 + j;
    if(RIN){ a[n1].re = in[base + e*estride]; a[n1].im = 0.f; }
    else { const float2* ci = (const float2*)in; float2 t2 = ci[base + e*estride]; a[n1].re=t2.x; a[n1].im=t2.y; }
  }
  c32 A[8];
  dft8<SIGN>(a, A);
  #pragma unroll
  for(int k1=0;k1<8;k1++){
    float ang = SIGN * (TWOPI/64.f) * (float)(j*k1);
    float sn, cs; __sincosf(ang, &sn, &cs);
    c32 t; t.re = A[k1].re*cs - A[k1].im*sn; t.im = A[k1].re*sn + A[k1].im*cs;
    tmp[ll][k1*8+j] = t;
  }
  __syncthreads();
  c32 bv[8];
  #pragma unroll
  for(int n2=0;n2<8;n2++) bv[n2] = tmp[ll][j*8+n2];
  c32 Y[8];
  dft8<SIGN>(bv, Y);
  #pragma unroll
  for(int k2=0;k2<8;k2++){
    int e = j + 8*k2;
    int oi = base + e*estride;
    if(ROUT) out[oi] = Y[k2].re*scale;
    else { float2* co = (float2*)out; co[oi] = make_float2(Y[k2].re*scale, Y[k2].im*scale); }
  }
}

// 128-pt FFT along channel axis, in-place; 16 lines/block x 16 threads
template<int SIGN>
__global__ void fft128_kernel(float* data, float scale){
  __shared__ c32 tmp[16][129];
  int ll = threadIdx.x & 15;
  int j  = threadIdx.x >> 4;   // n2 = 0..15
  int l = blockIdx.x*16 + ll;  // 0..16383 : (b, hf*64+wf)
  int b = l >> 12;
  int rem = l & 4095;
  size_t base = (size_t)b*CM*HW + rem;
  float2* cd = (float2*)data;
  c32 a[8];
  #pragma unroll
  for(int n1=0;n1<8;n1++){
    float2 t2 = cd[base + (size_t)(16*n1 + j)*HW];
    a[n1].re=t2.x; a[n1].im=t2.y;
  }
  c32 A[8];
  dft8<SIGN>(a, A);
  #pragma unroll
  for(int k1=0;k1<8;k1++){
    float ang = SIGN*(TWOPI/128.f)*(float)(j*k1);
    float sn,cs; __sincosf(ang,&sn,&cs);
    c32 t; t.re = A[k1].re*cs - A[k1].im*sn; t.im = A[k1].re*sn + A[k1].im*cs;
    tmp[ll][k1*16 + j] = t;
  }
  __syncthreads();
  int k1 = j & 7, half = j >> 3;
  c32 bv[16];
  #pragma unroll
  for(int n2=0;n2<16;n2++) bv[n2] = tmp[ll][k1*16+n2];
  #pragma unroll
  for(int kk=0;kk<8;kk++){
    int k2 = half*8 + kk;
    float xr=0.f, xi=0.f;
    #pragma unroll
    for(int n2=0;n2<16;n2++){
      float ang = SIGN*(TWOPI/16.f)*(float)((n2*k2)&15);
      float sn,cs; __sincosf(ang,&sn,&cs);
      xr += bv[n2].re*cs - bv[n2].im*sn;
      xi += bv[n2].re*sn + bv[n2].im*cs;
    }
    cd[base + (size_t)(k1 + 8*k2)*HW] = make_float2(xr*scale, xi*scale);
  }
}

// ---------------- channel-mixing einsum (+batch FFT4 + mask) ----------------
// out_ft[kb,o,f] = sum_i Xb[kb,i,f]*w1[i,o,f] ; Xb = FFT4 over batch of Xf
// v6: REVERTED to the round-0 form — best measured (212us). v2/v4/v5
// restructures (occupancy, SW-pipeline, contiguous-w) all landed 230-251us:
// the 536MB w1 stream through the ~50% L3-hit mix plateaus at ~2.5TB/s
// effective regardless of access structure. Declared local plateau.
__global__ void einsum_kernel(const float2* __restrict__ Xf, const float* __restrict__ w1r,
                              const float* __restrict__ w1i, float2* __restrict__ OutF){
  int fl = threadIdx.x & 63;
  int ol = threadIdx.x >> 6;   // 0..3
  int fbase = blockIdx.y*64;
  int obase = blockIdx.x*16;
  int f = fbase + fl;
  __shared__ float2 xs[4][64];
  c32 acc[4][4];               // [oj][kb]
  #pragma unroll
  for(int a1=0;a1<4;a1++)
    #pragma unroll
    for(int a2=0;a2<4;a2++){ acc[a1][a2].re=0.f; acc[a1][a2].im=0.f; }
  for(int i=0;i<CM;i++){
    __syncthreads();
    xs[ol][fl] = Xf[((size_t)(ol*CM + i))*HW + f];
    __syncthreads();
    float2 x0=xs[0][fl], x1=xs[1][fl], x2=xs[2][fl], x3=xs[3][fl];
    // FFT-4 over batch, sign -1 (scale folded into c-pass)
    c32 Xb[4];
    Xb[0].re = x0.x+x1.x+x2.x+x3.x;      Xb[0].im = x0.y+x1.y+x2.y+x3.y;
    Xb[1].re = x0.x + x1.y - x2.x - x3.y; Xb[1].im = x0.y - x1.x - x2.y + x3.x;
    Xb[2].re = x0.x - x1.x + x2.x - x3.x; Xb[2].im = x0.y - x1.y + x2.y - x3.y;
    Xb[3].re = x0.x - x1.y - x2.x + x3.y; Xb[3].im = x0.y + x1.x - x2.y - x3.x;
    #pragma unroll
    for(int oj=0;oj<4;oj++){
      int o = obase + oj*4 + ol;
      size_t wi_ = ((size_t)(i*CM + o))*HW + f;
      float wr = w1r[wi_], wim = w1i[wi_];
      #pragma unroll
      for(int kb=0;kb<4;kb++){
        acc[oj][kb].re += Xb[kb].re*wr - Xb[kb].im*wim;
        acc[oj][kb].im += Xb[kb].re*wim + Xb[kb].im*wr;
      }
    }
  }
  int hf = f>>6, wf = f&63;
  bool masked = (hf<3 || hf>60) && (wf<3 || wf>60);
  #pragma unroll
  for(int oj=0;oj<4;oj++){
    int o = obase + oj*4 + ol;
    #pragma unroll
    for(int kb=0;kb<4;kb++){
      float2 t2 = masked ? make_float2(0.f,0.f) : make_float2(acc[oj][kb].re, acc[oj][kb].im);
      OutF[((size_t)(kb*CM + o))*HW + f] = t2;
    }
  }
}

// ---------------- final combine: w0 conv + blend + bn2 + relu ----------------
// v6: oc-coverage 8 -> 32 per block (grid.y 16 -> 4): xatt re-read 16x -> 4x
// (xatt = 8MB > 4MB per-XCD L2, so the redundancy was L3-priced).
__global__ void final_kernel(const float* __restrict__ G, const float* __restrict__ xatt,
                             const float* __restrict__ w0, const float* __restrict__ w0b,
                             const float* __restrict__ r1p, const float* __restrict__ r2p,
                             const float* __restrict__ g2, const float* __restrict__ b2,
                             const float* __restrict__ m2, const float* __restrict__ v2,
                             float* __restrict__ yout){
  int p = blockIdx.x*256 + threadIdx.x;  // 0..4095
  int ocb = blockIdx.y*32; int b = blockIdx.z;
  float r1 = r1p[0], r2 = r2p[0];
  float acc[32];
  #pragma unroll
  for(int j=0;j<32;j++) acc[j]=0.f;
  const float* xb = xatt + (size_t)b*CM*HW + p;
  for(int ic=0; ic<CM; ic++){
    float xv = xb[(size_t)ic*HW];
    #pragma unroll
    for(int j=0;j<32;j++) acc[j] += xv * w0[(ocb+j)*CM + ic];
  }
  #pragma unroll
  for(int j=0;j<32;j++){
    int oc = ocb+j;
    float fam = r1 * G[((size_t)(b*CM+oc))*HW + p] + r2*(acc[j] + w0b[oc]);
    float s = g2[oc]*rsqrtf(v2[oc]+EPSF);
    float bi = b2[oc] - m2[oc]*s;
    float val = fam*s + bi;
    yout[((size_t)(b*CM+oc))*HW + p] = val>0.f?val:0.f;
  }
}

extern "C" void kernel_launch(void* const* d_in, const int* in_sizes, int n_in,
                              void* d_out, int out_size, void* d_ws, size_t ws_size,
                              hipStream_t stream){
  const float* x       = (const float*)d_in[0];
  const float* y       = (const float*)d_in[1];
  const float* conv1_w = (const float*)d_in[2];
  const float* bn1_g   = (const float*)d_in[3];
  const float* bn1_b   = (const float*)d_in[4];
  const float* bn1_m   = (const float*)d_in[5];
  const float* bn1_v   = (const float*)d_in[6];
  const float* q_w     = (const float*)d_in[7];
  const float* k_w     = (const float*)d_in[8];
  const float* v_w     = (const float*)d_in[9];
  const float* rel_h   = (const float*)d_in[10];
  const float* rel_w   = (const float*)d_in[11];
  const float* rate1   = (const float*)d_in[12];
  const float* rate2   = (const float*)d_in[13];
  const float* w1r     = (const float*)d_in[14];
  const float* w1i     = (const float*)d_in[15];
  const float* w0_w    = (const float*)d_in[16];
  const float* w0_b    = (const float*)d_in[17];
  const float* bn2_g   = (const float*)d_in[18];
  const float* bn2_b   = (const float*)d_in[19];
  const float* bn2_m   = (const float*)d_in[20];
  const float* bn2_v   = (const float*)d_in[21];
  (void)in_sizes; (void)n_in; (void)out_size; (void)ws_size;

  char* ws = (char*)d_ws;
  // phase-1 buffers (dead before complex buffers are written)
  float* Y1 = (float*)(ws + 0);                 // 2 MB
  float* Q  = (float*)(ws + 2097152);           // 8 MB
  float* K  = (float*)(ws + 10485760);           // 8.7 MB
  float* V  = (float*)(ws + 19406848);          // 8.7 MB (ends 28,327,936)
  // phase-2 buffers
  float2* E = (float2*)(ws + 0);                // 16 MB  (Xf)
  float2* F = (float2*)(ws + 16777216);         // 16 MB  (out_ft) -> peak ws = 32 MB
  float*  G = (float*)(ws + 0);                 // 8 MB real ifft result (over dead E)

  float* yout = (float*)d_out;
  float* xatt = (float*)d_out + 2097152;

  conv1_kernel<<<dim3(4,16,BB),256,0,stream>>>(y, conv1_w, bn1_g,bn1_b,bn1_m,bn1_v, Y1);
  qconv_kernel<<<dim3(16,4,BB),256,0,stream>>>(Y1, q_w, Q);
  kvconv_kernel<<<dim3(18,4,BB),256,0,stream>>>(x, k_w, v_w, K, V);
  attn_kernel<<<dim3(8192),256,0,stream>>>(Q, K, V, rel_h, rel_w, xatt);

  // forward 2D FFT over (h,w): real xatt -> E, then in-place along h
  fft64_kernel<-1,true,false><<<dim3(1024),256,0,stream>>>(xatt, (float*)E, 64,4096,64, 1, 0.125f);
  fft64_kernel<-1,false,false><<<dim3(1024),256,0,stream>>>((float*)E, (float*)E, 64,4096,1, 64, 0.125f);
  // forward FFT along channel (scale includes 1/sqrt(128) and batch 1/2)
  fft128_kernel<-1><<<dim3(1024),256,0,stream>>>((float*)E, 0.044194173824159216f);
  // batch FFT4 + channel-mix + mask
  einsum_kernel<<<dim3(8,64),256,0,stream>>>(E, w1r, w1i, F);
  // inverse 2D FFT over (h,w): in-place along h, then along w -> real G
  fft64_kernel<1,false,false><<<dim3(1024),256,0,stream>>>((float*)F, (float*)F, 64,4096,1, 64, 0.125f);
  fft64_kernel<1,false,true><<<dim3(1024),256,0,stream>>>((float*)F, G, 64,4096,64, 1, 0.125f);

  final_kernel<<<dim3(16,4,BB),256,0,stream>>>(G, xatt, w0_w, w0_b, rate1, rate2,
                                               bn2_g,bn2_b,bn2_m,bn2_v, yout);
}

// Round 9
// 782.117 us; speedup vs baseline: 1.1473x; 1.1473x over previous
//
#include <hip/hip_runtime.h>

#define BB 4
#define CY 256
#define CM 128
#define HW 4096       // 64*64
#define HWy 1024      // 32*32
#define PHW 4356      // 66*66
#define EPSF 1e-5f
#define TWOPI 6.2831853071795864769f

struct c32 { float re, im; };

// ---------------- conv kernels ----------------

__global__ void conv1_kernel(const float* __restrict__ y, const float* __restrict__ w,
                             const float* __restrict__ g, const float* __restrict__ bb,
                             const float* __restrict__ m, const float* __restrict__ v,
                             float* __restrict__ y1){
  int p = blockIdx.x*256 + threadIdx.x;   // 0..1023
  int ocb = blockIdx.y*8;
  int b = blockIdx.z;
  float acc[8] = {0,0,0,0,0,0,0,0};
  const float* yb = y + (size_t)b*CY*HWy + p;
  #pragma unroll 4
  for(int ic=0; ic<CY; ic++){
    float xv = yb[(size_t)ic*HWy];
    #pragma unroll
    for(int j=0;j<8;j++) acc[j] += xv * w[(ocb+j)*CY + ic];
  }
  #pragma unroll
  for(int j=0;j<8;j++){
    int oc = ocb+j;
    float s = g[oc]*rsqrtf(v[oc]+EPSF);
    float bi = bb[oc] - m[oc]*s;
    float r = acc[j]*s + bi;
    y1[((size_t)(b*CM+oc))*HWy + p] = r>0.f?r:0.f;
  }
}

// v7: adjacent output pair (p, p+1) shares the SAME source index mi
// (nearest-neighbor 2x upsample) -> compute once, write float2(acc,acc).
// Thread count halved; results bitwise identical to v0.
__global__ void qconv_kernel(const float* __restrict__ y1, const float* __restrict__ w,
                             float* __restrict__ q){
  int t = blockIdx.x*256 + threadIdx.x;  // 0..2047 (pair index)
  int p0 = t*2;                          // even p
  int ocb = blockIdx.y*8; int b = blockIdx.z;
  int mi = ((p0>>7)<<5) + ((p0&63)>>1);  // (h/2)*32 + w/2 (same for p0,p0+1)
  float acc[8] = {0,0,0,0,0,0,0,0};
  const float* yb = y1 + (size_t)b*CM*HWy + mi;
  #pragma unroll 4
  for(int ic=0; ic<CM; ic++){
    float xv = yb[(size_t)ic*HWy];
    #pragma unroll
    for(int j=0;j<8;j++) acc[j] += xv * w[(ocb+j)*CM+ic];
  }
  #pragma unroll
  for(int j=0;j<8;j++){
    float2* qo = (float2*)(q + ((size_t)(b*CM+ocb+j))*HW + p0);
    *qo = make_float2(acc[j], acc[j]);
  }
}

__global__ void kvconv_kernel(const float* __restrict__ x, const float* __restrict__ kw,
                              const float* __restrict__ vw,
                              float* __restrict__ k, float* __restrict__ v){
  int p = blockIdx.x*256 + threadIdx.x;  // 0..4355 (guard)
  int ocb = blockIdx.y*8; int b = blockIdx.z;
  if(p >= PHW) return;
  int hh = p/66, ww2 = p - hh*66;
  int ih = hh-1, iw = ww2-1;
  bool inb = (ih>=0 && ih<64 && iw>=0 && iw<64);
  float acck[8] = {0,0,0,0,0,0,0,0};
  float accv[8] = {0,0,0,0,0,0,0,0};
  if(inb){
    const float* xb = x + (size_t)b*CM*HW + ih*64 + iw;
    #pragma unroll 4
    for(int ic=0; ic<CM; ic++){
      float xv = xb[(size_t)ic*HW];
      #pragma unroll
      for(int j=0;j<8;j++){ acck[j] += xv*kw[(ocb+j)*CM+ic]; accv[j] += xv*vw[(ocb+j)*CM+ic]; }
    }
  }
  #pragma unroll
  for(int j=0;j<8;j++){
    size_t o = ((size_t)(b*CM+ocb+j))*PHW + p;
    k[o]=acck[j]; v[o]=accv[j];
  }
}

// ---------------- attention ----------------

__global__ void attn_kernel(const float* __restrict__ q, const float* __restrict__ k,
                            const float* __restrict__ v, const float* __restrict__ relh,
                            const float* __restrict__ relw, float* __restrict__ xatt){
  int t = blockIdx.x*256 + threadIdx.x;  // over B*CM*HW
  int p = t & 4095;
  int bc = t >> 12;       // b*128+c
  int c = bc & 127;
  int h = p>>6, w2 = p&63;
  float qv = q[(size_t)bc*HW + p];
  const float* kb = k + (size_t)bc*PHW;
  const float* vb = v + (size_t)bc*PHW;
  float lg[9], vv[9];
  #pragma unroll
  for(int ti=0; ti<3; ti++){
    #pragma unroll
    for(int tj=0; tj<3; tj++){
      int idx = (h+ti)*66 + (w2+tj);
      float rel = (c<64) ? relh[c*3+ti] : relw[(c-64)*3+tj];
      float kv = kb[idx] + rel;
      lg[ti*3+tj] = qv*kv;
      vv[ti*3+tj] = vb[idx];
    }
  }
  float mx = lg[0];
  #pragma unroll
  for(int i=1;i<9;i++) mx = fmaxf(mx, lg[i]);
  float s=0.f, o=0.f;
  #pragma unroll
  for(int i=0;i<9;i++){ float e = __expf(lg[i]-mx); s += e; o += e*vv[i]; }
  xatt[t] = o/s;
}

// ---------------- FFT helpers ----------------

template<int SIGN>
__device__ inline void dft8(const c32* a, c32* X){
  constexpr float C8[8] = {1.f,0.70710678118654752f,0.f,-0.70710678118654752f,
                           -1.f,-0.70710678118654752f,0.f,0.70710678118654752f};
  constexpr float S8[8] = {0.f,0.70710678118654752f,1.f,0.70710678118654752f,
                           0.f,-0.70710678118654752f,-1.f,-0.70710678118654752f};
  #pragma unroll
  for(int kk=0;kk<8;kk++){
    float xr=0.f, xi=0.f;
    #pragma unroll
    for(int n=0;n<8;n++){
      const int j=(n*kk)&7;
      const float wr = C8[j];
      const float wi = SIGN*S8[j];   // e^{SIGN*2pi i j/8}
      xr += a[n].re*wr - a[n].im*wi;
      xi += a[n].re*wi + a[n].im*wr;
    }
    X[kk].re=xr; X[kk].im=xi;
  }
}

// 64-pt FFT along an axis; 32 lines/block x 8 threads; line l: base=(l/l_div)*s1+(l%l_div)*s2
template<int SIGN, bool RIN, bool ROUT>
__global__ void fft64_kernel(const float* in, float* out,
                             int l_div, int s1, int s2, int estride, float scale){
  __shared__ c32 tmp[32][65];
  int ll = threadIdx.x & 31;
  int j  = threadIdx.x >> 5;   // n2 in pass1, k1 in pass2
  int l = blockIdx.x*32 + ll;
  int base = (l/l_div)*s1 + (l%l_div)*s2;
  c32 a[8];
  #pragma unroll
  for(int n1=0;n1<8;n1++){
    int e = n1*8 + j;
    if(RIN){ a[n1].re = in[base + e*estride]; a[n1].im = 0.f; }
    else { const float2* ci = (const float2*)in; float2 t2 = ci[base + e*estride]; a[n1].re=t2.x; a[n1].im=t2.y; }
  }
  c32 A[8];
  dft8<SIGN>(a, A);
  #pragma unroll
  for(int k1=0;k1<8;k1++){
    float ang = SIGN * (TWOPI/64.f) * (float)(j*k1);
    float sn, cs; __sincosf(ang, &sn, &cs);
    c32 t; t.re = A[k1].re*cs - A[k1].im*sn; t.im = A[k1].re*sn + A[k1].im*cs;
    tmp[ll][k1*8+j] = t;
  }
  __syncthreads();
  c32 bv[8];
  #pragma unroll
  for(int n2=0;n2<8;n2++) bv[n2] = tmp[ll][j*8+n2];
  c32 Y[8];
  dft8<SIGN>(bv, Y);
  #pragma unroll
  for(int k2=0;k2<8;k2++){
    int e = j + 8*k2;
    int oi = base + e*estride;
    if(ROUT) out[oi] = Y[k2].re*scale;
    else { float2* co = (float2*)out; co[oi] = make_float2(Y[k2].re*scale, Y[k2].im*scale); }
  }
}

// 128-pt FFT along channel axis, in-place; 16 lines/block x 16 threads
template<int SIGN>
__global__ void fft128_kernel(float* data, float scale){
  __shared__ c32 tmp[16][129];
  int ll = threadIdx.x & 15;
  int j  = threadIdx.x >> 4;   // n2 = 0..15
  int l = blockIdx.x*16 + ll;  // 0..16383 : (b, hf*64+wf)
  int b = l >> 12;
  int rem = l & 4095;
  size_t base = (size_t)b*CM*HW + rem;
  float2* cd = (float2*)data;
  c32 a[8];
  #pragma unroll
  for(int n1=0;n1<8;n1++){
    float2 t2 = cd[base + (size_t)(16*n1 + j)*HW];
    a[n1].re=t2.x; a[n1].im=t2.y;
  }
  c32 A[8];
  dft8<SIGN>(a, A);
  #pragma unroll
  for(int k1=0;k1<8;k1++){
    float ang = SIGN*(TWOPI/128.f)*(float)(j*k1);
    float sn,cs; __sincosf(ang,&sn,&cs);
    c32 t; t.re = A[k1].re*cs - A[k1].im*sn; t.im = A[k1].re*sn + A[k1].im*cs;
    tmp[ll][k1*16 + j] = t;
  }
  __syncthreads();
  int k1 = j & 7, half = j >> 3;
  c32 bv[16];
  #pragma unroll
  for(int n2=0;n2<16;n2++) bv[n2] = tmp[ll][k1*16+n2];
  #pragma unroll
  for(int kk=0;kk<8;kk++){
    int k2 = half*8 + kk;
    float xr=0.f, xi=0.f;
    #pragma unroll
    for(int n2=0;n2<16;n2++){
      float ang = SIGN*(TWOPI/16.f)*(float)((n2*k2)&15);
      float sn,cs; __sincosf(ang,&sn,&cs);
      xr += bv[n2].re*cs - bv[n2].im*sn;
      xi += bv[n2].re*sn + bv[n2].im*cs;
    }
    cd[base + (size_t)(k1 + 8*k2)*HW] = make_float2(xr*scale, xi*scale);
  }
}

// ---------------- channel-mixing einsum (+batch FFT4 + mask) ----------------
// out_ft[kb,o,f] = sum_i Xb[kb,i,f]*w1[i,o,f] ; Xb = FFT4 over batch of Xf
// Round-0 form — best measured (212us). All restructures (occupancy,
// SW-pipeline, contiguous-w) landed 230-251us: the 536MB w1 stream through
// the ~50% L3-hit mix plateaus regardless of access structure. Plateau.
__global__ void einsum_kernel(const float2* __restrict__ Xf, const float* __restrict__ w1r,
                              const float* __restrict__ w1i, float2* __restrict__ OutF){
  int fl = threadIdx.x & 63;
  int ol = threadIdx.x >> 6;   // 0..3
  int fbase = blockIdx.y*64;
  int obase = blockIdx.x*16;
  int f = fbase + fl;
  __shared__ float2 xs[4][64];
  c32 acc[4][4];               // [oj][kb]
  #pragma unroll
  for(int a1=0;a1<4;a1++)
    #pragma unroll
    for(int a2=0;a2<4;a2++){ acc[a1][a2].re=0.f; acc[a1][a2].im=0.f; }
  for(int i=0;i<CM;i++){
    __syncthreads();
    xs[ol][fl] = Xf[((size_t)(ol*CM + i))*HW + f];
    __syncthreads();
    float2 x0=xs[0][fl], x1=xs[1][fl], x2=xs[2][fl], x3=xs[3][fl];
    // FFT-4 over batch, sign -1 (scale folded into c-pass)
    c32 Xb[4];
    Xb[0].re = x0.x+x1.x+x2.x+x3.x;      Xb[0].im = x0.y+x1.y+x2.y+x3.y;
    Xb[1].re = x0.x + x1.y - x2.x - x3.y; Xb[1].im = x0.y - x1.x - x2.y + x3.x;
    Xb[2].re = x0.x - x1.x + x2.x - x3.x; Xb[2].im = x0.y - x1.y + x2.y - x3.y;
    Xb[3].re = x0.x - x1.y - x2.x + x3.y; Xb[3].im = x0.y + x1.x - x2.y - x3.x;
    #pragma unroll
    for(int oj=0;oj<4;oj++){
      int o = obase + oj*4 + ol;
      size_t wi_ = ((size_t)(i*CM + o))*HW + f;
      float wr = w1r[wi_], wim = w1i[wi_];
      #pragma unroll
      for(int kb=0;kb<4;kb++){
        acc[oj][kb].re += Xb[kb].re*wr - Xb[kb].im*wim;
        acc[oj][kb].im += Xb[kb].re*wim + Xb[kb].im*wr;
      }
    }
  }
  int hf = f>>6, wf = f&63;
  bool masked = (hf<3 || hf>60) && (wf<3 || wf>60);
  #pragma unroll
  for(int oj=0;oj<4;oj++){
    int o = obase + oj*4 + ol;
    #pragma unroll
    for(int kb=0;kb<4;kb++){
      float2 t2 = masked ? make_float2(0.f,0.f) : make_float2(acc[oj][kb].re, acc[oj][kb].im);
      OutF[((size_t)(kb*CM + o))*HW + f] = t2;
    }
  }
}

// ---------------- final combine: w0 conv + blend + bn2 + relu ----------------
// v7: float2 along p (p0 even -> all accesses 8B-aligned): the 16x xatt
// re-read stream moves in 512B/wave requests instead of 256B. Grid 512
// blocks (2/CU) — the occupancy at which einsum sustains its best rate.
// Per-output ic accumulation order unchanged -> bitwise identical.
__global__ void final_kernel(const float* __restrict__ G, const float* __restrict__ xatt,
                             const float* __restrict__ w0, const float* __restrict__ w0b,
                             const float* __restrict__ r1p, const float* __restrict__ r2p,
                             const float* __restrict__ g2, const float* __restrict__ b2,
                             const float* __restrict__ m2, const float* __restrict__ v2,
                             float* __restrict__ yout){
  int t = blockIdx.x*256 + threadIdx.x;  // 0..2047 (pair index)
  int p0 = t*2;
  int ocb = blockIdx.y*8; int b = blockIdx.z;
  float r1 = r1p[0], r2 = r2p[0];
  float2 acc[8];
  #pragma unroll
  for(int j=0;j<8;j++) acc[j] = make_float2(0.f,0.f);
  const float* xb = xatt + (size_t)b*CM*HW + p0;
  #pragma unroll 4
  for(int ic=0; ic<CM; ic++){
    float2 xv = *(const float2*)(xb + (size_t)ic*HW);
    #pragma unroll
    for(int j=0;j<8;j++){
      float wv = w0[(ocb+j)*CM + ic];
      acc[j].x += xv.x * wv;
      acc[j].y += xv.y * wv;
    }
  }
  #pragma unroll
  for(int j=0;j<8;j++){
    int oc = ocb+j;
    float2 g = *(const float2*)(G + ((size_t)(b*CM+oc))*HW + p0);
    float s = g2[oc]*rsqrtf(v2[oc]+EPSF);
    float bi = b2[oc] - m2[oc]*s;
    float f0 = (r1*g.x + r2*(acc[j].x + w0b[oc]))*s + bi;
    float f1 = (r1*g.y + r2*(acc[j].y + w0b[oc]))*s + bi;
    float2* yo = (float2*)(yout + ((size_t)(b*CM+oc))*HW + p0);
    *yo = make_float2(f0>0.f?f0:0.f, f1>0.f?f1:0.f);
  }
}

extern "C" void kernel_launch(void* const* d_in, const int* in_sizes, int n_in,
                              void* d_out, int out_size, void* d_ws, size_t ws_size,
                              hipStream_t stream){
  const float* x       = (const float*)d_in[0];
  const float* y       = (const float*)d_in[1];
  const float* conv1_w = (const float*)d_in[2];
  const float* bn1_g   = (const float*)d_in[3];
  const float* bn1_b   = (const float*)d_in[4];
  const float* bn1_m   = (const float*)d_in[5];
  const float* bn1_v   = (const float*)d_in[6];
  const float* q_w     = (const float*)d_in[7];
  const float* k_w     = (const float*)d_in[8];
  const float* v_w     = (const float*)d_in[9];
  const float* rel_h   = (const float*)d_in[10];
  const float* rel_w   = (const float*)d_in[11];
  const float* rate1   = (const float*)d_in[12];
  const float* rate2   = (const float*)d_in[13];
  const float* w1r     = (const float*)d_in[14];
  const float* w1i     = (const float*)d_in[15];
  const float* w0_w    = (const float*)d_in[16];
  const float* w0_b    = (const float*)d_in[17];
  const float* bn2_g   = (const float*)d_in[18];
  const float* bn2_b   = (const float*)d_in[19];
  const float* bn2_m   = (const float*)d_in[20];
  const float* bn2_v   = (const float*)d_in[21];
  (void)in_sizes; (void)n_in; (void)out_size; (void)ws_size;

  char* ws = (char*)d_ws;
  // phase-1 buffers (dead before complex buffers are written)
  float* Y1 = (float*)(ws + 0);                 // 2 MB
  float* Q  = (float*)(ws + 2097152);           // 8 MB
  float* K  = (float*)(ws + 10485760);          // 8.7 MB
  float* V  = (float*)(ws + 19406848);          // 8.7 MB (ends 28,327,936)
  // phase-2 buffers
  float2* E = (float2*)(ws + 0);                // 16 MB  (Xf)
  float2* F = (float2*)(ws + 16777216);         // 16 MB  (out_ft) -> peak ws = 32 MB
  float*  G = (float*)(ws + 0);                 // 8 MB real ifft result (over dead E)

  float* yout = (float*)d_out;
  float* xatt = (float*)d_out + 2097152;

  conv1_kernel<<<dim3(4,16,BB),256,0,stream>>>(y, conv1_w, bn1_g,bn1_b,bn1_m,bn1_v, Y1);
  qconv_kernel<<<dim3(8,16,BB),256,0,stream>>>(Y1, q_w, Q);
  kvconv_kernel<<<dim3(18,16,BB),256,0,stream>>>(x, k_w, v_w, K, V);
  attn_kernel<<<dim3(8192),256,0,stream>>>(Q, K, V, rel_h, rel_w, xatt);

  // forward 2D FFT over (h,w): real xatt -> E, then in-place along h
  fft64_kernel<-1,true,false><<<dim3(1024),256,0,stream>>>(xatt, (float*)E, 64,4096,64, 1, 0.125f);
  fft64_kernel<-1,false,false><<<dim3(1024),256,0,stream>>>((float*)E, (float*)E, 64,4096,1, 64, 0.125f);
  // forward FFT along channel (scale includes 1/sqrt(128) and batch 1/2)
  fft128_kernel<-1><<<dim3(1024),256,0,stream>>>((float*)E, 0.044194173824159216f);
  // batch FFT4 + channel-mix + mask
  einsum_kernel<<<dim3(8,64),256,0,stream>>>(E, w1r, w1i, F);
  // inverse 2D FFT over (h,w): in-place along h, then along w -> real G
  fft64_kernel<1,false,false><<<dim3(1024),256,0,stream>>>((float*)F, (float*)F, 64,4096,1, 64, 0.125f);
  fft64_kernel<1,false,true><<<dim3(1024),256,0,stream>>>((float*)F, G, 64,4096,64, 1, 0.125f);

  final_kernel<<<dim3(8,16,BB),256,0,stream>>>(G, xatt, w0_w, w0_b, rate1, rate2,
                                               bn2_g,bn2_b,bn2_m,bn2_v, yout);
}